// Round 20
// baseline (42.694 us; speedup 1.0000x reference)
//
#include <hip/hip_runtime.h>
#include <hip/hip_bf16.h>
#include <hip/hip_fp16.h>

// AdaCoF frame interpolation. R20: R19 + 3-buffer (A/B/C) streaming prefetch.
//  R19 ledger: stall-balanced (VALU 24%, LDS 43%, VMEM 16%), no saturated
//  pipe; 4 rounds of <=1.5%. Last untried lever: __syncthreads drains
//  vmcnt(0), so pre-barrier prefetches complete at the barrier and the A/B
//  ping-pong sustains only 15 loads in flight post-barrier. A third buffer
//  keeps 30 loads (2 groups) in flight during the middle taps: +15 VGPR
//  (40 -> ~55), still inside the <=64-reg / 32-waves-per-CU class.
//  All else R19 verbatim: 32x16 tile, 512-thr blocks, 1024-block grid,
//  fp16 winA(c0,c1) + pair-dup half2 c2 (3 ds_read2/tap), window-relative
//  corner math on the materialized replication-padded window, deferred
//  softmax normalization, fp16 ws partials + combine2h.
//  Tripwires: VGPR <= 64 (class edge), WRITE ~3.2 MB (no spill),
//  absmax <= 5e-3. If null -> practical floor; declare next round.

#define KS 5
#define K2 25
#define PADR 2

constexpr int T_ = 2;
constexpr int B_ = 4;
constexpr int C_ = 3;
constexpr int H_ = 256;
constexpr int W_ = 256;
constexpr int HW_ = H_ * W_;
constexpr int BCHW_ = B_ * C_ * HW_;                  // 786432
constexpr float HP_MAX = (float)(H_ + 2 * PADR - 1);  // 259
constexpr float WP_MAX = (float)(W_ + 2 * PADR - 1);  // 259
constexpr float HP_M2 = (float)(H_ + 2 * PADR - 2);   // 258
constexpr float WP_M2 = (float)(W_ + 2 * PADR - 2);   // 258

constexpr int TILE_W = 32;
constexpr int TILE_H = 16;
constexpr int HALO   = 8;
constexpr int RPAD   = HALO + PADR;            // 10
constexpr int WROWS  = TILE_H + 21;            // 37
constexpr int WCOLS  = TILE_W + 21;            // 53
constexpr int PLANE  = WROWS * WCOLS;          // 1961
constexpr int NTILE  = HW_ / (TILE_W * TILE_H);  // 128

__global__ __launch_bounds__(512) void adacof_tile(
    const float* __restrict__ frames,   // [T,B,C,H,W]
    const float* __restrict__ weights,  // [B,T,K2,H,W]
    const float* __restrict__ alphas,   // [B,T,K2,H,W]
    const float* __restrict__ betas,    // [B,T,K2,H,W]
    const float* __restrict__ occl,     // [B,T,H,W]
    __half* __restrict__ part)          // ws: [T,B,C,H,W] fp16
{
    __shared__ __half2 winA[PLANE];     // (c0,c1) at x:          7.8 KB
    __shared__ __half2 win2[PLANE];     // (c2 at x, c2 at x+1):  7.8 KB

    // block decode: 1024 blocks = b(4) x tile(128) x t(2)
    const int bid  = blockIdx.x;
    const int b    = bid >> 8;
    const int rem  = bid & 255;
    const int t    = rem & 1;
    const int tile = rem >> 1;          // 0..127 = ty(16) x tx(8)
    const int i0   = (tile >> 3) << 4;  // row tile * 16
    const int j0   = (tile & 7) << 5;   // col tile * 32

    const int tid = threadIdx.x;        // 0..511
    const int wy0 = i0 - RPAD;
    const int wx0 = j0 - RPAD;

    const float* __restrict__ fb = frames + (size_t)(t * B_ + b) * C_ * HW_;

    // ---- stage window = materialized replication-padded image ----
    for (int e = tid; e < PLANE; e += 512) {
        const int wy = e / WCOLS;               // const-div -> magic mul
        const int wx = e - wy * WCOLS;
        const int gy  = min(max(wy0 + wy, 0), H_ - 1);
        const int gx  = min(max(wx0 + wx, 0), W_ - 1);
        const int gx1 = min(max(wx0 + wx + 1, 0), W_ - 1);
        const int gr = gy << 8;
        winA[e] = __floats2half2_rn(fb[gr + gx], fb[HW_ + gr + gx]);
        win2[e] = __floats2half2_rn(fb[2 * HW_ + gr + gx], fb[2 * HW_ + gr + gx1]);
    }

    const int x = tid & 31, r = tid >> 5;   // r = 0..15
    const int i = i0 + r, j = j0 + x;
    const int ij = (i << 8) | j;

    const int btbase = ((b * T_ + t) * K2) * HW_ + ij;
    const float* __restrict__ wp = weights + btbase;
    const float* __restrict__ ap = alphas + btbase;
    const float* __restrict__ bp = betas + btbase;

    // occlusion loads issued early, consumed in epilogue
    const float o_own = occl[(b * T_ + t) * HW_ + ij];
    const float o_oth = occl[(b * T_ + (1 - t)) * HW_ + ij];

    float wsum = 0.0f, acc0 = 0.0f, acc1 = 0.0f, acc2 = 0.0f;
    const float fi = (float)i;
    const float fj = (float)j;
    const float oy = (float)(i0 - HALO);   // window-origin: iy = y0f - oy
    const float ox = (float)(j0 - HALO);

    // ---- 3-buffer prefetch (literal-indexed after unroll; no runtime idx) ----
    float wgA[5], agA[5], bgA[5];
    float wgB[5], agB[5], bgB[5];
    float wgC[5], agC[5], bgC[5];

#define PREFETCH(BUF, BASE)                                                    \
    {                                                                          \
        _Pragma("unroll")                                                      \
        for (int q = 0; q < 5; ++q) {                                          \
            wg##BUF[q] = wp[((BASE) + q) * HW_];                               \
            ag##BUF[q] = ap[((BASE) + q) * HW_];                               \
            bg##BUF[q] = bp[((BASE) + q) * HW_];                               \
        }                                                                      \
    }

#define TAP5(BUF, BASE)                                                        \
    {                                                                          \
        _Pragma("unroll")                                                      \
        for (int q = 0; q < 5; ++q) {                                          \
            const int k = (BASE) + q;                                          \
            const float ew = __expf(wg##BUF[q]);                               \
            wsum += ew;                                                        \
            const int kd = k / KS;                                             \
            const float dy = (float)kd;                                        \
            const float dx = (float)(k - kd * KS);                             \
            const float y2  = fminf(fmaxf(ag##BUF[q] + (dy + fi), 0.0f), HP_MAX); \
            const float x2  = fminf(fmaxf(bg##BUF[q] + (dx + fj), 0.0f), WP_MAX); \
            const float y0f = fminf(floorf(y2), HP_M2);                        \
            const float x0f = fminf(floorf(x2), WP_M2);                        \
            const float fy  = y2 - y0f;                                        \
            const float fx  = x2 - x0f;                                        \
            const int iy  = (int)(y0f - oy);                                   \
            const int ixx = (int)(x0f - ox);                                   \
            const int l   = iy * WCOLS + ixx;                                  \
            const float fyw = fy * ew;                                         \
            const float ey0 = ew - fyw;                                        \
            const float w01 = fx * ey0;                                        \
            const float w00 = ey0 - w01;                                       \
            const float w11 = fx * fyw;                                        \
            const float w10 = fyw - w11;                                       \
            const float2 p00 = __half22float2(winA[l]);                        \
            const float2 p01 = __half22float2(winA[l + 1]);                    \
            const float2 p10 = __half22float2(winA[l + WCOLS]);                \
            const float2 p11 = __half22float2(winA[l + WCOLS + 1]);            \
            const float2 q0  = __half22float2(win2[l]);                        \
            const float2 q1  = __half22float2(win2[l + WCOLS]);                \
            acc0 += w00 * p00.x + w01 * p01.x + w10 * p10.x + w11 * p11.x;     \
            acc1 += w00 * p00.y + w01 * p01.y + w10 * p10.y + w11 * p11.y;     \
            acc2 += w00 * q0.x  + w01 * q0.y  + w10 * q1.x  + w11 * q1.y;      \
        }                                                                      \
    }

    // pre-barrier groups complete at the barrier (vmcnt drained by sync);
    // the 3rd buffer is what sustains 2 groups in flight POST-barrier.
    PREFETCH(A, 0)
    PREFETCH(B, 5)
    PREFETCH(C, 10)

    __syncthreads();

    TAP5(A, 0)
    PREFETCH(A, 15)
    TAP5(B, 5)
    PREFETCH(B, 20)
    TAP5(C, 10)      // A(15) + B(20) both in flight here (30 loads)
    TAP5(A, 15)
    TAP5(B, 20)

#undef PREFETCH
#undef TAP5

    const float occw = 1.0f / (1.0f + __expf(o_oth - o_own));
    const float wscale = occw / wsum;

    // fp16 partials: values normalized (<=1), +5e-4 err, half the ws traffic
    __half* __restrict__ pt = part + ((size_t)(t * B_ + b) * C_) * HW_ + ij;
    pt[0]       = __float2half(acc0 * wscale);
    pt[HW_]     = __float2half(acc1 * wscale);
    pt[2 * HW_] = __float2half(acc2 * wscale);
}

__global__ void combine2h(const __half2* __restrict__ part,
                          float2* __restrict__ out) {
    const int n = blockIdx.x * blockDim.x + threadIdx.x;   // over BCHW/2
    const float2 a = __half22float2(part[n]);
    const float2 c = __half22float2(part[n + BCHW_ / 2]);
    out[n] = make_float2(a.x + c.x, a.y + c.y);
}

extern "C" void kernel_launch(void* const* d_in, const int* in_sizes, int n_in,
                              void* d_out, int out_size, void* d_ws, size_t ws_size,
                              hipStream_t stream) {
    const float* frames  = (const float*)d_in[0];
    const float* weights = (const float*)d_in[1];
    const float* alphas  = (const float*)d_in[2];
    const float* betas   = (const float*)d_in[3];
    const float* occl    = (const float*)d_in[4];
    float* out = (float*)d_out;
    __half* part = (__half*)d_ws;        // 3.1 MB fp16; ws_size ample

    const int blocks = B_ * T_ * NTILE;  // 1024 blocks x 512 threads
    adacof_tile<<<blocks, 512, 0, stream>>>(frames, weights, alphas, betas,
                                            occl, part);
    combine2h<<<(BCHW_ / 2) / 256, 256, 0, stream>>>((const __half2*)part,
                                                     (float2*)out);
}

// Round 21
// 37.600 us; speedup vs baseline: 1.1355x; 1.1355x over previous
//
#include <hip/hip_runtime.h>
#include <hip/hip_bf16.h>
#include <hip/hip_fp16.h>

// AdaCoF frame interpolation. R21 = R19 reverted (proven best, 38.1 us).
//  R20 refuted 3-buffer prefetch: VGPR 72 crossed the 64-reg class edge at
//  8-wave blocks -> occupancy 20% -> 42.7 us. Final structure:
//   - two-kernel t-split: 1024 blocks x 512 thr (4 blocks/CU, 32 waves/CU
//     class) + tiny combine2h.
//   - block = 32x16 pixel tile x one t; window 53x37 (halo +-8, single
//     path, clamp-insured) staged in LDS as the materialized replication-
//     padded image: winA = half2(c0,c1), win2 = pair-dup half2(c2 x, x+1)
//     -> 3 ds_read2_b32 / 6 dwords per tap (fp16 packing floor).
//   - window-relative corner math (no read-side clamps/remap).
//   - deferred softmax normalization (occw/wsum applied once in epilogue).
//   - 5-deep A/B ping-pong streaming prefetch (literal-indexed regs).
//   - fp16 ws partials (values normalized; +5e-4 err vs 15.7e-3 threshold).
//  Stall-balanced floor: VALU 24% / LDS 43% / VMEM 16%, no saturated pipe;
//  remaining gap to the ~14.5 us LDS-pipe bound is chained dependency
//  latency across 25 short taps, not a removable pipe cost.

#define KS 5
#define K2 25
#define PADR 2

constexpr int T_ = 2;
constexpr int B_ = 4;
constexpr int C_ = 3;
constexpr int H_ = 256;
constexpr int W_ = 256;
constexpr int HW_ = H_ * W_;
constexpr int BCHW_ = B_ * C_ * HW_;                  // 786432
constexpr float HP_MAX = (float)(H_ + 2 * PADR - 1);  // 259
constexpr float WP_MAX = (float)(W_ + 2 * PADR - 1);  // 259
constexpr float HP_M2 = (float)(H_ + 2 * PADR - 2);   // 258
constexpr float WP_M2 = (float)(W_ + 2 * PADR - 2);   // 258

constexpr int TILE_W = 32;
constexpr int TILE_H = 16;
constexpr int HALO   = 8;
constexpr int RPAD   = HALO + PADR;            // 10
constexpr int WROWS  = TILE_H + 21;            // 37
constexpr int WCOLS  = TILE_W + 21;            // 53
constexpr int PLANE  = WROWS * WCOLS;          // 1961
constexpr int NTILE  = HW_ / (TILE_W * TILE_H);  // 128

__global__ __launch_bounds__(512) void adacof_tile(
    const float* __restrict__ frames,   // [T,B,C,H,W]
    const float* __restrict__ weights,  // [B,T,K2,H,W]
    const float* __restrict__ alphas,   // [B,T,K2,H,W]
    const float* __restrict__ betas,    // [B,T,K2,H,W]
    const float* __restrict__ occl,     // [B,T,H,W]
    __half* __restrict__ part)          // ws: [T,B,C,H,W] fp16
{
    __shared__ __half2 winA[PLANE];     // (c0,c1) at x:          7.8 KB
    __shared__ __half2 win2[PLANE];     // (c2 at x, c2 at x+1):  7.8 KB

    // block decode: 1024 blocks = b(4) x tile(128) x t(2)
    const int bid  = blockIdx.x;
    const int b    = bid >> 8;
    const int rem  = bid & 255;
    const int t    = rem & 1;
    const int tile = rem >> 1;          // 0..127 = ty(16) x tx(8)
    const int i0   = (tile >> 3) << 4;  // row tile * 16
    const int j0   = (tile & 7) << 5;   // col tile * 32

    const int tid = threadIdx.x;        // 0..511
    const int wy0 = i0 - RPAD;
    const int wx0 = j0 - RPAD;

    const float* __restrict__ fb = frames + (size_t)(t * B_ + b) * C_ * HW_;

    // ---- stage window = materialized replication-padded image ----
    for (int e = tid; e < PLANE; e += 512) {
        const int wy = e / WCOLS;               // const-div -> magic mul
        const int wx = e - wy * WCOLS;
        const int gy  = min(max(wy0 + wy, 0), H_ - 1);
        const int gx  = min(max(wx0 + wx, 0), W_ - 1);
        const int gx1 = min(max(wx0 + wx + 1, 0), W_ - 1);
        const int gr = gy << 8;
        winA[e] = __floats2half2_rn(fb[gr + gx], fb[HW_ + gr + gx]);
        win2[e] = __floats2half2_rn(fb[2 * HW_ + gr + gx], fb[2 * HW_ + gr + gx1]);
    }

    const int x = tid & 31, r = tid >> 5;   // r = 0..15
    const int i = i0 + r, j = j0 + x;
    const int ij = (i << 8) | j;

    const int btbase = ((b * T_ + t) * K2) * HW_ + ij;
    const float* __restrict__ wp = weights + btbase;
    const float* __restrict__ ap = alphas + btbase;
    const float* __restrict__ bp = betas + btbase;

    // occlusion loads issued early, consumed in epilogue
    const float o_own = occl[(b * T_ + t) * HW_ + ij];
    const float o_oth = occl[(b * T_ + (1 - t)) * HW_ + ij];

    float wsum = 0.0f, acc0 = 0.0f, acc1 = 0.0f, acc2 = 0.0f;
    const float fi = (float)i;
    const float fj = (float)j;
    const float oy = (float)(i0 - HALO);   // window-origin: iy = y0f - oy
    const float ox = (float)(j0 - HALO);

    // ---- 5-deep ping-pong prefetch buffers (literal-indexed after unroll) ----
    float wgA[5], agA[5], bgA[5];
    float wgB[5], agB[5], bgB[5];

#define PREFETCH(BUF, BASE)                                                    \
    {                                                                          \
        _Pragma("unroll")                                                      \
        for (int q = 0; q < 5; ++q) {                                          \
            wg##BUF[q] = wp[((BASE) + q) * HW_];                               \
            ag##BUF[q] = ap[((BASE) + q) * HW_];                               \
            bg##BUF[q] = bp[((BASE) + q) * HW_];                               \
        }                                                                      \
    }

#define TAP5(BUF, BASE)                                                        \
    {                                                                          \
        _Pragma("unroll")                                                      \
        for (int q = 0; q < 5; ++q) {                                          \
            const int k = (BASE) + q;                                          \
            const float ew = __expf(wg##BUF[q]);                               \
            wsum += ew;                                                        \
            const int kd = k / KS;                                             \
            const float dy = (float)kd;                                        \
            const float dx = (float)(k - kd * KS);                             \
            const float y2  = fminf(fmaxf(ag##BUF[q] + (dy + fi), 0.0f), HP_MAX); \
            const float x2  = fminf(fmaxf(bg##BUF[q] + (dx + fj), 0.0f), WP_MAX); \
            const float y0f = fminf(floorf(y2), HP_M2);                        \
            const float x0f = fminf(floorf(x2), WP_M2);                        \
            const float fy  = y2 - y0f;                                        \
            const float fx  = x2 - x0f;                                        \
            const int iy  = (int)(y0f - oy);                                   \
            const int ixx = (int)(x0f - ox);                                   \
            const int l   = iy * WCOLS + ixx;                                  \
            const float fyw = fy * ew;                                         \
            const float ey0 = ew - fyw;                                        \
            const float w01 = fx * ey0;                                        \
            const float w00 = ey0 - w01;                                       \
            const float w11 = fx * fyw;                                        \
            const float w10 = fyw - w11;                                       \
            const float2 p00 = __half22float2(winA[l]);                        \
            const float2 p01 = __half22float2(winA[l + 1]);                    \
            const float2 p10 = __half22float2(winA[l + WCOLS]);                \
            const float2 p11 = __half22float2(winA[l + WCOLS + 1]);            \
            const float2 q0  = __half22float2(win2[l]);                        \
            const float2 q1  = __half22float2(win2[l + WCOLS]);                \
            acc0 += w00 * p00.x + w01 * p01.x + w10 * p10.x + w11 * p11.x;     \
            acc1 += w00 * p00.y + w01 * p01.y + w10 * p10.y + w11 * p11.y;     \
            acc2 += w00 * q0.x  + w01 * q0.y  + w10 * q1.x  + w11 * q1.y;      \
        }                                                                      \
    }

    // groups 0,1 issued early; register dests stay in flight across barrier
    PREFETCH(A, 0)
    PREFETCH(B, 5)

    __syncthreads();

    TAP5(A, 0)
    PREFETCH(A, 10)
    TAP5(B, 5)
    PREFETCH(B, 15)
    TAP5(A, 10)
    PREFETCH(A, 20)
    TAP5(B, 15)
    TAP5(A, 20)

#undef PREFETCH
#undef TAP5

    const float occw = 1.0f / (1.0f + __expf(o_oth - o_own));
    const float wscale = occw / wsum;

    // fp16 partials: values normalized (<=1), +5e-4 err, half the ws traffic
    __half* __restrict__ pt = part + ((size_t)(t * B_ + b) * C_) * HW_ + ij;
    pt[0]       = __float2half(acc0 * wscale);
    pt[HW_]     = __float2half(acc1 * wscale);
    pt[2 * HW_] = __float2half(acc2 * wscale);
}

__global__ void combine2h(const __half2* __restrict__ part,
                          float2* __restrict__ out) {
    const int n = blockIdx.x * blockDim.x + threadIdx.x;   // over BCHW/2
    const float2 a = __half22float2(part[n]);
    const float2 c = __half22float2(part[n + BCHW_ / 2]);
    out[n] = make_float2(a.x + c.x, a.y + c.y);
}

extern "C" void kernel_launch(void* const* d_in, const int* in_sizes, int n_in,
                              void* d_out, int out_size, void* d_ws, size_t ws_size,
                              hipStream_t stream) {
    const float* frames  = (const float*)d_in[0];
    const float* weights = (const float*)d_in[1];
    const float* alphas  = (const float*)d_in[2];
    const float* betas   = (const float*)d_in[3];
    const float* occl    = (const float*)d_in[4];
    float* out = (float*)d_out;
    __half* part = (__half*)d_ws;        // 3.1 MB fp16; ws_size ample

    const int blocks = B_ * T_ * NTILE;  // 1024 blocks x 512 threads
    adacof_tile<<<blocks, 512, 0, stream>>>(frames, weights, alphas, betas,
                                            occl, part);
    combine2h<<<(BCHW_ / 2) / 256, 256, 0, stream>>>((const __half2*)part,
                                                     (float2*)out);
}